// Round 10
// baseline (215.037 us; speedup 1.0000x reference)
//
#include <hip/hip_runtime.h>
#include <hip/hip_bf16.h>

#define NANCH 202500
#define PRE_NMS 6000
#define POST_NMS 300
#define KW 94            // ceil(6016/64) words per supp row
#define CAP 8192
#define NBUCK 16384
#define BSHIFT 18
#define IOU_TH 0.7f
#define MIN_SIZE 0.016f
#define TB_PAD 6016      // topbox padded to a multiple of 64
#define RTILE 256        // rank j-tile (legacy fallback)
#define RITEMS 8         // candidates per thread (legacy fallback)
#define SBLK 256         // score grid blocks
#define CBLK 198         // compact blocks: ceil(202500/1024)

typedef unsigned long long ull;

// ---------------- shared decode / key helpers ---------------------------
__device__ inline float4 decode_box(const float* __restrict__ loc,
                                    const float* __restrict__ anc, int i) {
    float4 a = ((const float4*)anc)[i];
    float4 t = ((const float4*)loc)[i];
    float pw = a.z - a.x, ph = a.w - a.y;
    float pcx = (a.x + a.z) * 0.5f, pcy = (a.y + a.w) * 0.5f;
    float cx = t.x * pw + pcx, cy = t.y * ph + pcy;
    float w = expf(t.z) * pw, h = expf(t.w) * ph;
    float x1 = fminf(fmaxf(cx - 0.5f * w, 0.f), 1.f);
    float y1 = fminf(fmaxf(cy - 0.5f * h, 0.f), 1.f);
    float x2 = fminf(fmaxf(cx + 0.5f * w, 0.f), 1.f);
    float y2 = fminf(fmaxf(cy + 0.5f * h, 0.f), 1.f);
    return make_float4(x1, y1, x2, y2);
}

__device__ inline unsigned make_key(const float* __restrict__ cls,
                                    const float* __restrict__ loc,
                                    const float* __restrict__ anc, int i) {
    float2 c = ((const float2*)cls)[i];
    float d = c.y - c.x;                       // monotone proxy for softmax[:,1]
    float4 b = decode_box(loc, anc, i);
    bool valid = ((b.z - b.x) >= MIN_SIZE) && ((b.w - b.y) >= MIN_SIZE);
    unsigned ib = __float_as_uint(d);
    unsigned u = (ib & 0x80000000u) ? ~ib : (ib | 0x80000000u);  // monotonic key
    return valid ? u : 0u;                     // invalid -> below everything
}

__device__ inline ull orx64(ull v, int m) {    // OR-butterfly step (2x shfl_xor)
    unsigned lo = (unsigned)v, hi = (unsigned)(v >> 32);
    lo = (unsigned)__shfl_xor((int)lo, m, 64);
    hi = (unsigned)__shfl_xor((int)hi, m, 64);
    return ((ull)hi << 32) | lo;
}

// div-free IoU test (verified R4-F): iou>TH <=> inter>TH*(a+b-inter)
__device__ inline bool iou_gt(float4 bi, float4 bj, float ai) {
    float aj = (bj.z - bj.x) * (bj.w - bj.y);
    float lx = fmaxf(bi.x, bj.x), ly = fmaxf(bi.y, bj.y);
    float rx = fminf(bi.z, bj.z), ry = fminf(bi.w, bj.w);
    float iw = fmaxf(rx - lx, 0.f), ih = fmaxf(ry - ly, 0.f);
    float inter = iw * ih;
    return inter > IOU_TH * (ai + aj - inter);
}

// ---------------- K1: keys + per-block LDS histogram ---------------------
__global__ __launch_bounds__(256) void k_score(const float* __restrict__ cls,
                                               const float* __restrict__ loc,
                                               const float* __restrict__ anc,
                                               unsigned* __restrict__ hist,
                                               unsigned* __restrict__ keyc, int n) {
    __shared__ unsigned lh[NBUCK];             // 64 KB
    int tid = threadIdx.x, bid = blockIdx.x;
    for (int q = tid; q < NBUCK; q += 256) lh[q] = 0u;
    __syncthreads();
    for (int i = bid * 256 + tid; i < n; i += SBLK * 256) {
        unsigned u = make_key(cls, loc, anc, i);
        if (keyc) keyc[i] = u;
        atomicAdd(&lh[u >> BSHIFT], 1u);
    }
    __syncthreads();
    for (int qq = 0; qq < NBUCK / 256; qq++) {
        int q = (qq + bid) & (NBUCK / 256 - 1);     // stagger across blocks
        int b = q * 256 + tid;
        unsigned v = lh[b];
        if (v) atomicAdd(&hist[b], v);
    }
}

// ---------------- K2: compact, inline findb + block-scan placement ------
// (R6-verified: 198 same-address atomics instead of ~2800)
__global__ __launch_bounds__(256) void k_compactB(const unsigned* __restrict__ keyc,
                                                  const unsigned* __restrict__ hist,
                                                  unsigned* __restrict__ meta,
                                                  ull* __restrict__ cand, int n) {
    __shared__ unsigned ps[256];
    __shared__ unsigned Bs;
    __shared__ unsigned wbase[5];
    int tid = threadIdx.x, bid = blockIdx.x;
    const uint4* h4 = (const uint4*)hist;
    unsigned local = 0;
    #pragma unroll
    for (int b = 0; b < 16; b++) {             // 64 buckets per thread
        uint4 v = h4[tid * 16 + b];
        local += v.x + v.y + v.z + v.w;
    }
    ps[tid] = local;
    __syncthreads();
    for (int off = 1; off < 256; off <<= 1) {  // suffix sum
        unsigned add = (tid + off < 256) ? ps[tid + off] : 0u;
        __syncthreads();
        ps[tid] += add;
        __syncthreads();
    }
    unsigned incl = ps[tid];
    unsigned excl = incl - local;
    if (incl >= (unsigned)PRE_NMS && excl < (unsigned)PRE_NMS) {
        unsigned hv[64];
        #pragma unroll
        for (int b = 0; b < 16; b++) {
            uint4 v = h4[tid * 16 + b];
            hv[4 * b] = v.x; hv[4 * b + 1] = v.y;
            hv[4 * b + 2] = v.z; hv[4 * b + 3] = v.w;
        }
        unsigned cum = excl;
        int B = tid * 64;
        for (int b = 63; b >= 0; b--) {
            cum += hv[b];
            if (cum >= (unsigned)PRE_NMS) { B = tid * 64 + b; break; }
        }
        Bs = (unsigned)B;
    }
    __syncthreads();
    unsigned B = Bs;
    int lane = tid & 63, wv = tid >> 6;
    unsigned uk[4]; bool pr[4]; unsigned lpre[4], kpre[4];
    ull ltm = (1ull << lane) - 1ull;
    unsigned wsum = 0;
    #pragma unroll
    for (int k = 0; k < 4; k++) {
        int i = bid * 1024 + k * 256 + tid;
        unsigned u = (i < n) ? keyc[i] : 0u;
        uk[k] = u;
        bool pred = (i < n) && ((u >> BSHIFT) >= B);
        pr[k] = pred;
        ull m = __ballot(pred);
        lpre[k] = (unsigned)__popcll(m & ltm);
        kpre[k] = wsum;
        wsum += (unsigned)__popcll(m);
    }
    if (lane == 0) wbase[wv] = wsum;
    __syncthreads();
    if (tid == 0) {                            // scan 4 wave totals + ONE atomic
        unsigned s = 0;
        #pragma unroll
        for (int w = 0; w < 4; w++) { unsigned t = wbase[w]; wbase[w] = s; s += t; }
        wbase[4] = atomicAdd(&meta[1], s);
    }
    __syncthreads();
    unsigned base = wbase[4] + wbase[wv];
    #pragma unroll
    for (int k = 0; k < 4; k++) {
        if (pr[k]) {
            unsigned p = base + kpre[k] + lpre[k];
            if (p < CAP)
                cand[p] = ((ull)(~uk[k]) << 32) | (unsigned)(bid * 1024 + k * 256 + tid);
        }
    }
}

// ---------------- K3: fused exact-rank + scatter (R6-verified) ----------
__global__ __launch_bounds__(256) void k_ranksc(const ull* __restrict__ cand,
                                                const unsigned* __restrict__ meta,
                                                const float* __restrict__ loc,
                                                const float* __restrict__ anc,
                                                float4* __restrict__ topbox,
                                                ull* __restrict__ vmask) {
    __shared__ __align__(16) ull tile[256];    // 2 KB
    int tid = threadIdx.x, bid = blockIdx.x;
    unsigned C = meta[1]; if (C > CAP) C = CAP;
    int sub = tid >> 3, octl = tid & 7;
    int ci = bid * 32 + sub;                   // 256 blocks x 32 == CAP
    ull ki = (ci < (int)C) ? cand[ci] : 0ull;
    unsigned cnt = 0;
    int ntile = ((int)C + 255) / 256;          // uniform across grid
    for (int tt = 0; tt < ntile; tt++) {
        int j = tt * 256 + tid;
        tile[tid] = (j < (int)C) ? cand[j] : ~0ull;   // pad never < real key
        __syncthreads();
        #pragma unroll
        for (int jj = 0; jj < 32; jj++)
            cnt += (unsigned)(tile[jj * 8 + octl] < ki);
        __syncthreads();
    }
    cnt += (unsigned)__shfl_xor((int)cnt, 1, 64);     // octet reduce
    cnt += (unsigned)__shfl_xor((int)cnt, 2, 64);
    cnt += (unsigned)__shfl_xor((int)cnt, 4, 64);
    if (octl == 0 && ci < (int)C) {
        unsigned uu = ~(unsigned)(ki >> 32);
        if (uu != 0u && cnt < (unsigned)PRE_NMS) {
            topbox[cnt] = decode_box(loc, anc, (int)(unsigned)ki);
            atomicOr(&vmask[cnt >> 6], 1ull << (cnt & 63));
        }
    }
}

// ---------------- K4: supp tiles (transposed) + last-block R9 scan ------
// R9 postmortem: ~60us of the remaining 106 sits in ~6 graph-node
// boundaries (~10us each; R4's k_front phase-work sum ~18us proves the
// kernel work is small). The only phase that fits the last-block fusion
// pattern is the 1-block scan. R8's fusion regression was its REDESIGNED
// scan (always-issue gathers, ~90us standalone) — here the R9-verified
// scan is kept byte-for-byte. sdg[] deleted: with suppT layout the diag
// word is suppT[c*TB_PAD+row], contiguous + coalesced.
// Completion: rowc[rb] (64B-padded, target KW-rb) then meta[2] (target KW);
// no spins -> no deadlock possible; counters re-zeroed by per-call memset.
__global__ __launch_bounds__(64) void k_suppscan(const float4* __restrict__ topbox,
                                                 ull* __restrict__ suppT,
                                                 const ull* __restrict__ vmask,
                                                 float* __restrict__ out,
                                                 unsigned* __restrict__ meta,
                                                 unsigned* __restrict__ rowc) {
    __shared__ float4 cbox[64];
    __shared__ int klist[POST_NMS + 64];
    __shared__ ull vm_s[KW];
    int cb = blockIdx.x, rb = blockIdx.y, l = threadIdx.x;
    if (cb < rb) return;                        // lower tri: no work, no count
    int i = rb * 64 + l;
    int jt = cb * 64 + l;
    cbox[l] = (jt < PRE_NMS) ? topbox[jt] : make_float4(0.f, 0.f, 0.f, 0.f);
    __syncthreads();
    if (i < PRE_NMS) {
        float4 bi = topbox[i];
        float ai = (bi.z - bi.x) * (bi.w - bi.y);
        ull bits = 0ull;
        int j0 = cb * 64;
        for (int jj = 0; jj < 64; jj++) {
            int j = j0 + jj;
            if (j <= i || j >= PRE_NMS) continue;
            if (iou_gt(bi, cbox[jj], ai)) bits |= (1ull << jj);
        }
        suppT[(size_t)cb * TB_PAD + i] = bits;  // coalesced across lanes
    }
    // ---- completion: two-level counters; last block runs the scan ----
    __syncthreads();
    unsigned amlast = 0;
    if (l == 0) {
        __threadfence();                       // release: publish suppT
        if (atomicAdd(&rowc[rb * 16], 1u) == (unsigned)(KW - rb - 1))
            if (atomicAdd(&meta[2], 1u) == (unsigned)(KW - 1))
                amlast = 1;
    }
    amlast = (unsigned)__shfl((int)amlast, 0, 64);
    if (!amlast) return;
    __threadfence();                           // acquire: see all suppT

    // ---------------- serial scan (R9-verified, verbatim) ----------------
    for (int q = l; q < KW; q += 64) vm_s[q] = vmask[q];
    __syncthreads();
    int nk = 0;
    for (int c = 0; c < KW && nk < POST_NMS; c++) {
        ull vm = vm_s[c];
        if (!vm) continue;
        int row = c * 64 + l;
        const ull* col = suppT + (size_t)c * TB_PAD;
        ull sd = (row < PRE_NMS) ? col[row] : 0ull;   // diag word, coalesced
        ull inc = 0ull;                        // union of prior keeps' word c
        for (int q = l; q < nk; q += 64)
            inc |= col[klist[q]];
        #pragma unroll
        for (int off = 32; off; off >>= 1) inc |= orx64(inc, off);
        ull todo = vm & ~inc;
        unsigned tlo = __builtin_amdgcn_readfirstlane((unsigned)todo);
        unsigned thi = __builtin_amdgcn_readfirstlane((unsigned)(todo >> 32));
        ull td = ((ull)thi << 32) | tlo;       // scalar domain
        if (!td) continue;
        unsigned sdlo = (unsigned)sd, sdhi = (unsigned)(sd >> 32);
        ull keepw = 0ull;
        while (td) {                           // one scalar iteration per keep
            int b = __builtin_ctzll(td);
            unsigned mlo = __builtin_amdgcn_readlane(sdlo, b);
            unsigned mhi = __builtin_amdgcn_readlane(sdhi, b);
            ull m = (((ull)mhi << 32) | mlo) | (1ull << b);
            keepw |= 1ull << b;
            td &= ~m;
        }
        // parallel klist append: bit order == rank order
        int pos = nk + (int)__popcll(keepw & ((1ull << l) - 1ull));
        if ((keepw >> l) & 1ull) klist[pos] = row;
        nk += (int)__popcll(keepw);
        __syncthreads();
    }
    __syncthreads();
    int nout = nk < POST_NMS ? nk : POST_NMS;
    for (int q = l; q < nout; q += 64)
        ((float4*)out)[q] = topbox[klist[q]];
    for (int q = nout + l; q < POST_NMS; q += 64)
        ((float4*)out)[q] = make_float4(0.f, 0.f, 0.f, 0.f);
}

// ======================= legacy kernels (small-ws fallback) ==============
__global__ __launch_bounds__(1024) void k_findb(const unsigned* __restrict__ hist,
                                                unsigned* __restrict__ meta) {
    __shared__ unsigned ps[1024];
    int t = threadIdx.x;
    int base = t * (NBUCK / 1024);
    unsigned local = 0;
    for (int b = 0; b < NBUCK / 1024; b++) local += hist[base + b];
    ps[t] = local;
    __syncthreads();
    for (int off = 1; off < 1024; off <<= 1) {
        unsigned add = (t + off < 1024) ? ps[t + off] : 0u;
        __syncthreads();
        ps[t] += add;
        __syncthreads();
    }
    unsigned incl = ps[t];
    unsigned excl = incl - local;
    if (incl >= (unsigned)PRE_NMS && excl < (unsigned)PRE_NMS) {
        unsigned cum = excl;
        int B = base;
        for (int b = NBUCK / 1024 - 1; b >= 0; b--) {
            cum += hist[base + b];
            if (cum >= (unsigned)PRE_NMS) { B = base + b; break; }
        }
        meta[0] = (unsigned)B;
    }
}

__global__ __launch_bounds__(256) void k_compactR(const float* __restrict__ cls,
                                                  const float* __restrict__ loc,
                                                  const float* __restrict__ anc,
                                                  unsigned* __restrict__ meta,
                                                  ull* __restrict__ cand, int n) {
    int i = blockIdx.x * blockDim.x + threadIdx.x;
    if (i >= n) return;
    unsigned u = make_key(cls, loc, anc, i);
    if ((u >> BSHIFT) >= meta[0]) {
        unsigned p = atomicAdd(&meta[1], 1u);
        if (p < CAP) cand[p] = ((ull)(~u) << 32) | (unsigned)i;
    }
}

__global__ __launch_bounds__(256) void k_rank(const ull* __restrict__ cand,
                                              const unsigned* __restrict__ meta,
                                              unsigned* __restrict__ rank,
                                              float4* __restrict__ topbox) {
    __shared__ __align__(16) ull tile[RTILE];
    int tid = threadIdx.x;
    int bx = blockIdx.x, by = blockIdx.y;
    unsigned C = meta[1]; if (C > CAP) C = CAP;
    if (by == 0) {                             // sentinel prefill (k_nms fallback)
        int per = TB_PAD / (CAP / (256 * RITEMS));
        int s0 = bx * per;
        for (int q = tid; q < per; q += 256)
            topbox[s0 + q] = make_float4(-1.f, -1.f, -1.f, -1.f);
    }
    int ibase = bx * 256 * RITEMS;
    ull ki[RITEMS]; unsigned cnt[RITEMS];
    #pragma unroll
    for (int r = 0; r < RITEMS; r++) {
        int i = ibase + r * 256 + tid;
        ki[r] = (i < (int)C) ? cand[i] : ~0ull;
        cnt[r] = 0u;
    }
    int j = by * RTILE + tid;
    tile[tid] = (j < (int)C) ? cand[j] : ~0ull;
    __syncthreads();
    const ulonglong2* t2 = (const ulonglong2*)tile;
    for (int q = 0; q < RTILE / 2; q++) {
        ulonglong2 v = t2[q];
        #pragma unroll
        for (int r = 0; r < RITEMS; r++)
            cnt[r] += (unsigned)(v.x < ki[r]) + (unsigned)(v.y < ki[r]);
    }
    #pragma unroll
    for (int r = 0; r < RITEMS; r++)
        if (cnt[r]) atomicAdd(&rank[ibase + r * 256 + tid], cnt[r]);
}

__global__ __launch_bounds__(256) void k_scatter(const ull* __restrict__ cand,
                                                 const unsigned* __restrict__ meta,
                                                 const unsigned* __restrict__ rank,
                                                 const float* __restrict__ loc,
                                                 const float* __restrict__ anc,
                                                 float4* __restrict__ topbox,
                                                 ull* __restrict__ vmask) {
    int i = blockIdx.x * 256 + threadIdx.x;
    unsigned C = meta[1]; if (C > CAP) C = CAP;
    if (i >= (int)C) return;
    ull kv = cand[i];
    unsigned uu = ~(unsigned)(kv >> 32);
    if (uu == 0u) return;
    unsigned r = rank[i];
    if (r >= PRE_NMS) return;
    int idx = (int)(unsigned)kv;
    topbox[r] = decode_box(loc, anc, idx);
    atomicOr(&vmask[r >> 6], 1ull << (r & 63));
}

__global__ __launch_bounds__(64) void k_nms(const float4* __restrict__ topbox,
                                            float* __restrict__ out) {
    int l = threadIdx.x;
    float4 kb[5];
    int nk = 0;
    for (int q0 = 0; q0 < TB_PAD && nk < POST_NMS; q0 += 64) {
        float4 myb = topbox[q0 + l];
        for (int b = 0; b < 64 && nk < POST_NMS; b++) {
            float4 bb;
            bb.x = __shfl(myb.x, b, 64);
            bb.y = __shfl(myb.y, b, 64);
            bb.z = __shfl(myb.z, b, 64);
            bb.w = __shfl(myb.w, b, 64);
            if (bb.x < 0.f) continue;
            float ab = (bb.z - bb.x) * (bb.w - bb.y);
            bool sup = false;
            #pragma unroll
            for (int r = 0; r < 5; r++) {
                int s = r * 64 + l;
                if (s < nk) {
                    float4 kv = kb[r];
                    float ak = (kv.z - kv.x) * (kv.w - kv.y);
                    float lx = fmaxf(bb.x, kv.x), ly = fmaxf(bb.y, kv.y);
                    float rx = fminf(bb.z, kv.z), ry = fminf(bb.w, kv.w);
                    float iw = fmaxf(rx - lx, 0.f), ih = fmaxf(ry - ly, 0.f);
                    float inter = iw * ih;
                    float iou = inter / (ab + ak - inter + 1e-12f);
                    sup |= (iou > IOU_TH);
                }
            }
            if (!__any(sup)) {
                if (l == (nk & 63)) kb[nk >> 6] = bb;
                if (l < 4) {
                    float v = (l == 0) ? bb.x : (l == 1) ? bb.y : (l == 2) ? bb.z : bb.w;
                    out[4 * nk + l] = v;
                }
                nk++;
            }
        }
    }
    for (int t = nk * 4 + l; t < POST_NMS * 4; t += 64) out[t] = 0.f;
}

extern "C" void kernel_launch(void* const* d_in, const int* in_sizes, int n_in,
                              void* d_out, int out_size, void* d_ws, size_t ws_size,
                              hipStream_t stream) {
    const int N = in_sizes[0] / 2;             // 202500
    const float* cls = (const float*)d_in[0];
    const float* loc = (const float*)d_in[1];
    const float* anc = (const float*)d_in[2];
    float* out = (float*)d_out;

    char* ws = (char*)d_ws;
    size_t off = 0;
    auto take = [&](size_t bytes) {
        size_t o = off;
        off += (bytes + 255) & ~(size_t)255;
        return o;
    };
    // zero-init region: hist + meta/vmask/rowc + rank, contiguous -> one memset
    unsigned* hist = (unsigned*)(ws + take((size_t)NBUCK * 4));      // 64 KB
    char*     mblk = ws + take(8192);
    unsigned* meta  = (unsigned*)mblk;                               // [0]=B [1]=count [2]=gctr
    ull*      vmask = (ull*)(mblk + 256);                            // 94 words
    unsigned* rowc  = (unsigned*)(mblk + 1024);                      // 94 ctrs, 64B-padded
    unsigned* rank = (unsigned*)(ws + take((size_t)CAP * 4));        // 32 KB (legacy)
    size_t zlen = off;
    // rest
    ull*    cand   = (ull*)(ws + take((size_t)CAP * 8));             // 64 KB
    float4* topbox = (float4*)(ws + take((size_t)TB_PAD * 16));      // 94 KB
    // fast-path extras
    unsigned* keyc = (unsigned*)(ws + take((size_t)N * 4));          // 810 KB
    ull*      suppT = (ull*)(ws + take((size_t)KW * TB_PAD * 8));    // 4.52 MB
    size_t full_need = off;
    const bool fast = (ws_size >= full_need);   // constant across calls -> graph-safe

    hipMemsetAsync(ws, 0, zlen, stream);

    if (fast) {
        // 5-node graph: memset, score, compactB, ranksc, suppscan(+last-block scan)
        k_score<<<SBLK, 256, 0, stream>>>(cls, loc, anc, hist, keyc, N);
        k_compactB<<<CBLK, 256, 0, stream>>>(keyc, hist, meta, cand, N);
        k_ranksc<<<CAP / 32, 256, 0, stream>>>(cand, meta, loc, anc, topbox, vmask);
        k_suppscan<<<dim3(KW, KW), 64, 0, stream>>>(topbox, suppT, vmask, out, meta, rowc);
    } else {
        dim3 rgrid(CAP / (256 * RITEMS), CAP / RTILE);
        k_score<<<SBLK, 256, 0, stream>>>(cls, loc, anc, hist, (unsigned*)nullptr, N);
        k_findb<<<1, 1024, 0, stream>>>(hist, meta);
        k_compactR<<<(N + 255) / 256, 256, 0, stream>>>(cls, loc, anc, meta, cand, N);
        k_rank<<<rgrid, 256, 0, stream>>>(cand, meta, rank, topbox);
        k_scatter<<<CAP / 256, 256, 0, stream>>>(cand, meta, rank, loc, anc, topbox, vmask);
        k_nms<<<1, 64, 0, stream>>>(topbox, out);
    }
}

// Round 11
// 146.884 us; speedup vs baseline: 1.4640x; 1.4640x over previous
//
#include <hip/hip_runtime.h>
#include <hip/hip_bf16.h>

#define NANCH 202500
#define PRE_NMS 6000
#define POST_NMS 300
#define KW 94            // ceil(6016/64) words per supp row
#define CAP 8192
#define NBUCK 16384
#define BSHIFT 18
#define IOU_TH 0.7f
#define MIN_SIZE 0.016f
#define TB_PAD 6016      // topbox padded to a multiple of 64
#define RTILE 256        // rank j-tile (legacy fallback)
#define RITEMS 8         // candidates per thread (legacy fallback)
#define SBLK 256         // score grid blocks
#define CBLK 198         // compact blocks: ceil(202500/1024)

typedef unsigned long long ull;

// ---------------- shared decode / key helpers ---------------------------
__device__ inline float4 decode_box(const float* __restrict__ loc,
                                    const float* __restrict__ anc, int i) {
    float4 a = ((const float4*)anc)[i];
    float4 t = ((const float4*)loc)[i];
    float pw = a.z - a.x, ph = a.w - a.y;
    float pcx = (a.x + a.z) * 0.5f, pcy = (a.y + a.w) * 0.5f;
    float cx = t.x * pw + pcx, cy = t.y * ph + pcy;
    float w = expf(t.z) * pw, h = expf(t.w) * ph;
    float x1 = fminf(fmaxf(cx - 0.5f * w, 0.f), 1.f);
    float y1 = fminf(fmaxf(cy - 0.5f * h, 0.f), 1.f);
    float x2 = fminf(fmaxf(cx + 0.5f * w, 0.f), 1.f);
    float y2 = fminf(fmaxf(cy + 0.5f * h, 0.f), 1.f);
    return make_float4(x1, y1, x2, y2);
}

__device__ inline unsigned make_key(const float* __restrict__ cls,
                                    const float* __restrict__ loc,
                                    const float* __restrict__ anc, int i) {
    float2 c = ((const float2*)cls)[i];
    float d = c.y - c.x;                       // monotone proxy for softmax[:,1]
    float4 b = decode_box(loc, anc, i);
    bool valid = ((b.z - b.x) >= MIN_SIZE) && ((b.w - b.y) >= MIN_SIZE);
    unsigned ib = __float_as_uint(d);
    unsigned u = (ib & 0x80000000u) ? ~ib : (ib | 0x80000000u);  // monotonic key
    return valid ? u : 0u;                     // invalid -> below everything
}

__device__ inline ull orx64(ull v, int m) {    // OR-butterfly step (2x shfl_xor)
    unsigned lo = (unsigned)v, hi = (unsigned)(v >> 32);
    lo = (unsigned)__shfl_xor((int)lo, m, 64);
    hi = (unsigned)__shfl_xor((int)hi, m, 64);
    return ((ull)hi << 32) | lo;
}

// div-free IoU test (verified R4-F): iou>TH <=> inter>TH*(a+b-inter)
__device__ inline bool iou_gt(float4 bi, float4 bj, float ai) {
    float aj = (bj.z - bj.x) * (bj.w - bj.y);
    float lx = fmaxf(bi.x, bj.x), ly = fmaxf(bi.y, bj.y);
    float rx = fminf(bi.z, bj.z), ry = fminf(bi.w, bj.w);
    float iw = fmaxf(rx - lx, 0.f), ih = fmaxf(ry - ly, 0.f);
    float inter = iw * ih;
    return inter > IOU_TH * (ai + aj - inter);
}

// ---------------- K1: keys + per-block LDS histogram ---------------------
__global__ __launch_bounds__(256) void k_score(const float* __restrict__ cls,
                                               const float* __restrict__ loc,
                                               const float* __restrict__ anc,
                                               unsigned* __restrict__ hist,
                                               unsigned* __restrict__ keyc, int n) {
    __shared__ unsigned lh[NBUCK];             // 64 KB
    int tid = threadIdx.x, bid = blockIdx.x;
    for (int q = tid; q < NBUCK; q += 256) lh[q] = 0u;
    __syncthreads();
    for (int i = bid * 256 + tid; i < n; i += SBLK * 256) {
        unsigned u = make_key(cls, loc, anc, i);
        if (keyc) keyc[i] = u;
        atomicAdd(&lh[u >> BSHIFT], 1u);
    }
    __syncthreads();
    for (int qq = 0; qq < NBUCK / 256; qq++) {
        int q = (qq + bid) & (NBUCK / 256 - 1);     // stagger across blocks
        int b = q * 256 + tid;
        unsigned v = lh[b];
        if (v) atomicAdd(&hist[b], v);
    }
}

// ---------------- K2: compact, inline findb + block-scan placement ------
// (R6-verified: 198 same-address atomics instead of ~2800)
__global__ __launch_bounds__(256) void k_compactB(const unsigned* __restrict__ keyc,
                                                  const unsigned* __restrict__ hist,
                                                  unsigned* __restrict__ meta,
                                                  ull* __restrict__ cand, int n) {
    __shared__ unsigned ps[256];
    __shared__ unsigned Bs;
    __shared__ unsigned wbase[5];
    int tid = threadIdx.x, bid = blockIdx.x;
    const uint4* h4 = (const uint4*)hist;
    unsigned local = 0;
    #pragma unroll
    for (int b = 0; b < 16; b++) {             // 64 buckets per thread
        uint4 v = h4[tid * 16 + b];
        local += v.x + v.y + v.z + v.w;
    }
    ps[tid] = local;
    __syncthreads();
    for (int off = 1; off < 256; off <<= 1) {  // suffix sum
        unsigned add = (tid + off < 256) ? ps[tid + off] : 0u;
        __syncthreads();
        ps[tid] += add;
        __syncthreads();
    }
    unsigned incl = ps[tid];
    unsigned excl = incl - local;
    if (incl >= (unsigned)PRE_NMS && excl < (unsigned)PRE_NMS) {
        unsigned hv[64];
        #pragma unroll
        for (int b = 0; b < 16; b++) {
            uint4 v = h4[tid * 16 + b];
            hv[4 * b] = v.x; hv[4 * b + 1] = v.y;
            hv[4 * b + 2] = v.z; hv[4 * b + 3] = v.w;
        }
        unsigned cum = excl;
        int B = tid * 64;
        for (int b = 63; b >= 0; b--) {
            cum += hv[b];
            if (cum >= (unsigned)PRE_NMS) { B = tid * 64 + b; break; }
        }
        Bs = (unsigned)B;
    }
    __syncthreads();
    unsigned B = Bs;
    int lane = tid & 63, wv = tid >> 6;
    unsigned uk[4]; bool pr[4]; unsigned lpre[4], kpre[4];
    ull ltm = (1ull << lane) - 1ull;
    unsigned wsum = 0;
    #pragma unroll
    for (int k = 0; k < 4; k++) {
        int i = bid * 1024 + k * 256 + tid;
        unsigned u = (i < n) ? keyc[i] : 0u;
        uk[k] = u;
        bool pred = (i < n) && ((u >> BSHIFT) >= B);
        pr[k] = pred;
        ull m = __ballot(pred);
        lpre[k] = (unsigned)__popcll(m & ltm);
        kpre[k] = wsum;
        wsum += (unsigned)__popcll(m);
    }
    if (lane == 0) wbase[wv] = wsum;
    __syncthreads();
    if (tid == 0) {                            // scan 4 wave totals + ONE atomic
        unsigned s = 0;
        #pragma unroll
        for (int w = 0; w < 4; w++) { unsigned t = wbase[w]; wbase[w] = s; s += t; }
        wbase[4] = atomicAdd(&meta[1], s);
    }
    __syncthreads();
    unsigned base = wbase[4] + wbase[wv];
    #pragma unroll
    for (int k = 0; k < 4; k++) {
        if (pr[k]) {
            unsigned p = base + kpre[k] + lpre[k];
            if (p < CAP)
                cand[p] = ((ull)(~uk[k]) << 32) | (unsigned)(bid * 1024 + k * 256 + tid);
        }
    }
}

// ---------------- K3: fused exact-rank + scatter (R6-verified) ----------
__global__ __launch_bounds__(256) void k_ranksc(const ull* __restrict__ cand,
                                                const unsigned* __restrict__ meta,
                                                const float* __restrict__ loc,
                                                const float* __restrict__ anc,
                                                float4* __restrict__ topbox,
                                                ull* __restrict__ vmask) {
    __shared__ __align__(16) ull tile[256];    // 2 KB
    int tid = threadIdx.x, bid = blockIdx.x;
    unsigned C = meta[1]; if (C > CAP) C = CAP;
    int sub = tid >> 3, octl = tid & 7;
    int ci = bid * 32 + sub;                   // 256 blocks x 32 == CAP
    ull ki = (ci < (int)C) ? cand[ci] : 0ull;
    unsigned cnt = 0;
    int ntile = ((int)C + 255) / 256;          // uniform across grid
    for (int tt = 0; tt < ntile; tt++) {
        int j = tt * 256 + tid;
        tile[tid] = (j < (int)C) ? cand[j] : ~0ull;   // pad never < real key
        __syncthreads();
        #pragma unroll
        for (int jj = 0; jj < 32; jj++)
            cnt += (unsigned)(tile[jj * 8 + octl] < ki);
        __syncthreads();
    }
    cnt += (unsigned)__shfl_xor((int)cnt, 1, 64);     // octet reduce
    cnt += (unsigned)__shfl_xor((int)cnt, 2, 64);
    cnt += (unsigned)__shfl_xor((int)cnt, 4, 64);
    if (octl == 0 && ci < (int)C) {
        unsigned uu = ~(unsigned)(ki >> 32);
        if (uu != 0u && cnt < (unsigned)PRE_NMS) {
            topbox[cnt] = decode_box(loc, anc, (int)(unsigned)ki);
            atomicOr(&vmask[cnt >> 6], 1ull << (cnt & 63));
        }
    }
}

// ---------------- K4: suppression, TRANSPOSED layout (R9-verified) ------
// R10 postmortem: last-block fused scan = +70us (reads resolve dirty lines
// across 8 non-coherent XCD L2s; kernel boundary's L2 writeback makes a
// SEPARATE scan kernel's reads L3-clean and ~3x faster). Fusion closed.
// suppT[cb*TB_PAD+i]: coalesced writes, diag word readable coalesced.
__global__ __launch_bounds__(64) void k_supp(const float4* __restrict__ topbox,
                                             ull* __restrict__ suppT,
                                             ull* __restrict__ sdg) {
    int cb = blockIdx.x, rb = blockIdx.y;
    if (cb < rb) return;                        // never read -> skip entirely
    int i = rb * 64 + threadIdx.x;
    __shared__ float4 cbox[64];
    int jt = cb * 64 + threadIdx.x;
    cbox[threadIdx.x] = (jt < PRE_NMS) ? topbox[jt] : make_float4(0.f, 0.f, 0.f, 0.f);
    __syncthreads();
    if (i >= PRE_NMS) return;
    float4 bi = topbox[i];
    float ai = (bi.z - bi.x) * (bi.w - bi.y);
    ull bits = 0ull;
    int j0 = cb * 64;
    for (int jj = 0; jj < 64; jj++) {
        int j = j0 + jj;
        if (j <= i || j >= PRE_NMS) continue;
        if (iou_gt(bi, cbox[jj], ai)) bits |= (1ull << jj);
    }
    suppT[(size_t)cb * TB_PAD + i] = bits;     // coalesced across lanes
    if (cb == rb) sdg[i] = bits;
}

// ---------------- K5: serial scan, scalar inner loop (R9-verified) ------
__global__ __launch_bounds__(64) void k_scan(const ull* __restrict__ suppT,
                                             const ull* __restrict__ sdg,
                                             const ull* __restrict__ vmask,
                                             const float4* __restrict__ topbox,
                                             float* __restrict__ out) {
    __shared__ int klist[POST_NMS + 64];       // last block may overshoot <64
    __shared__ ull vm_s[KW];
    int l = threadIdx.x;
    for (int q = l; q < KW; q += 64) vm_s[q] = vmask[q];
    __syncthreads();
    int nk = 0;
    for (int c = 0; c < KW && nk < POST_NMS; c++) {
        ull vm = vm_s[c];
        if (!vm) continue;
        int row = c * 64 + l;
        ull sd = (row < PRE_NMS) ? sdg[row] : 0ull;   // coalesced; issued early
        ull inc = 0ull;                        // union of prior keeps' word c
        const ull* col = suppT + (size_t)c * TB_PAD;
        for (int q = l; q < nk; q += 64)
            inc |= col[klist[q]];
        #pragma unroll
        for (int off = 32; off; off >>= 1) inc |= orx64(inc, off);
        ull todo = vm & ~inc;
        unsigned tlo = __builtin_amdgcn_readfirstlane((unsigned)todo);
        unsigned thi = __builtin_amdgcn_readfirstlane((unsigned)(todo >> 32));
        ull td = ((ull)thi << 32) | tlo;       // scalar domain
        if (!td) continue;
        unsigned sdlo = (unsigned)sd, sdhi = (unsigned)(sd >> 32);
        ull keepw = 0ull;
        while (td) {                           // one scalar iteration per keep
            int b = __builtin_ctzll(td);
            unsigned mlo = __builtin_amdgcn_readlane(sdlo, b);
            unsigned mhi = __builtin_amdgcn_readlane(sdhi, b);
            ull m = (((ull)mhi << 32) | mlo) | (1ull << b);
            keepw |= 1ull << b;
            td &= ~m;
        }
        // parallel klist append: bit order == rank order
        int pos = nk + (int)__popcll(keepw & ((1ull << l) - 1ull));
        if ((keepw >> l) & 1ull) klist[pos] = row;
        nk += (int)__popcll(keepw);
        __syncthreads();
    }
    __syncthreads();
    int nout = nk < POST_NMS ? nk : POST_NMS;
    for (int q = l; q < nout; q += 64)
        ((float4*)out)[q] = topbox[klist[q]];
    for (int q = nout + l; q < POST_NMS; q += 64)
        ((float4*)out)[q] = make_float4(0.f, 0.f, 0.f, 0.f);
}

// ======================= legacy kernels (small-ws fallback) ==============
__global__ __launch_bounds__(1024) void k_findb(const unsigned* __restrict__ hist,
                                                unsigned* __restrict__ meta) {
    __shared__ unsigned ps[1024];
    int t = threadIdx.x;
    int base = t * (NBUCK / 1024);
    unsigned local = 0;
    for (int b = 0; b < NBUCK / 1024; b++) local += hist[base + b];
    ps[t] = local;
    __syncthreads();
    for (int off = 1; off < 1024; off <<= 1) {
        unsigned add = (t + off < 1024) ? ps[t + off] : 0u;
        __syncthreads();
        ps[t] += add;
        __syncthreads();
    }
    unsigned incl = ps[t];
    unsigned excl = incl - local;
    if (incl >= (unsigned)PRE_NMS && excl < (unsigned)PRE_NMS) {
        unsigned cum = excl;
        int B = base;
        for (int b = NBUCK / 1024 - 1; b >= 0; b--) {
            cum += hist[base + b];
            if (cum >= (unsigned)PRE_NMS) { B = base + b; break; }
        }
        meta[0] = (unsigned)B;
    }
}

__global__ __launch_bounds__(256) void k_compactR(const float* __restrict__ cls,
                                                  const float* __restrict__ loc,
                                                  const float* __restrict__ anc,
                                                  unsigned* __restrict__ meta,
                                                  ull* __restrict__ cand, int n) {
    int i = blockIdx.x * blockDim.x + threadIdx.x;
    if (i >= n) return;
    unsigned u = make_key(cls, loc, anc, i);
    if ((u >> BSHIFT) >= meta[0]) {
        unsigned p = atomicAdd(&meta[1], 1u);
        if (p < CAP) cand[p] = ((ull)(~u) << 32) | (unsigned)i;
    }
}

__global__ __launch_bounds__(256) void k_rank(const ull* __restrict__ cand,
                                              const unsigned* __restrict__ meta,
                                              unsigned* __restrict__ rank,
                                              float4* __restrict__ topbox) {
    __shared__ __align__(16) ull tile[RTILE];
    int tid = threadIdx.x;
    int bx = blockIdx.x, by = blockIdx.y;
    unsigned C = meta[1]; if (C > CAP) C = CAP;
    if (by == 0) {                             // sentinel prefill (k_nms fallback)
        int per = TB_PAD / (CAP / (256 * RITEMS));
        int s0 = bx * per;
        for (int q = tid; q < per; q += 256)
            topbox[s0 + q] = make_float4(-1.f, -1.f, -1.f, -1.f);
    }
    int ibase = bx * 256 * RITEMS;
    ull ki[RITEMS]; unsigned cnt[RITEMS];
    #pragma unroll
    for (int r = 0; r < RITEMS; r++) {
        int i = ibase + r * 256 + tid;
        ki[r] = (i < (int)C) ? cand[i] : ~0ull;
        cnt[r] = 0u;
    }
    int j = by * RTILE + tid;
    tile[tid] = (j < (int)C) ? cand[j] : ~0ull;
    __syncthreads();
    const ulonglong2* t2 = (const ulonglong2*)tile;
    for (int q = 0; q < RTILE / 2; q++) {
        ulonglong2 v = t2[q];
        #pragma unroll
        for (int r = 0; r < RITEMS; r++)
            cnt[r] += (unsigned)(v.x < ki[r]) + (unsigned)(v.y < ki[r]);
    }
    #pragma unroll
    for (int r = 0; r < RITEMS; r++)
        if (cnt[r]) atomicAdd(&rank[ibase + r * 256 + tid], cnt[r]);
}

__global__ __launch_bounds__(256) void k_scatter(const ull* __restrict__ cand,
                                                 const unsigned* __restrict__ meta,
                                                 const unsigned* __restrict__ rank,
                                                 const float* __restrict__ loc,
                                                 const float* __restrict__ anc,
                                                 float4* __restrict__ topbox,
                                                 ull* __restrict__ vmask) {
    int i = blockIdx.x * 256 + threadIdx.x;
    unsigned C = meta[1]; if (C > CAP) C = CAP;
    if (i >= (int)C) return;
    ull kv = cand[i];
    unsigned uu = ~(unsigned)(kv >> 32);
    if (uu == 0u) return;
    unsigned r = rank[i];
    if (r >= PRE_NMS) return;
    int idx = (int)(unsigned)kv;
    topbox[r] = decode_box(loc, anc, idx);
    atomicOr(&vmask[r >> 6], 1ull << (r & 63));
}

__global__ __launch_bounds__(64) void k_nms(const float4* __restrict__ topbox,
                                            float* __restrict__ out) {
    int l = threadIdx.x;
    float4 kb[5];
    int nk = 0;
    for (int q0 = 0; q0 < TB_PAD && nk < POST_NMS; q0 += 64) {
        float4 myb = topbox[q0 + l];
        for (int b = 0; b < 64 && nk < POST_NMS; b++) {
            float4 bb;
            bb.x = __shfl(myb.x, b, 64);
            bb.y = __shfl(myb.y, b, 64);
            bb.z = __shfl(myb.z, b, 64);
            bb.w = __shfl(myb.w, b, 64);
            if (bb.x < 0.f) continue;
            float ab = (bb.z - bb.x) * (bb.w - bb.y);
            bool sup = false;
            #pragma unroll
            for (int r = 0; r < 5; r++) {
                int s = r * 64 + l;
                if (s < nk) {
                    float4 kv = kb[r];
                    float ak = (kv.z - kv.x) * (kv.w - kv.y);
                    float lx = fmaxf(bb.x, kv.x), ly = fmaxf(bb.y, kv.y);
                    float rx = fminf(bb.z, kv.z), ry = fminf(bb.w, kv.w);
                    float iw = fmaxf(rx - lx, 0.f), ih = fmaxf(ry - ly, 0.f);
                    float inter = iw * ih;
                    float iou = inter / (ab + ak - inter + 1e-12f);
                    sup |= (iou > IOU_TH);
                }
            }
            if (!__any(sup)) {
                if (l == (nk & 63)) kb[nk >> 6] = bb;
                if (l < 4) {
                    float v = (l == 0) ? bb.x : (l == 1) ? bb.y : (l == 2) ? bb.z : bb.w;
                    out[4 * nk + l] = v;
                }
                nk++;
            }
        }
    }
    for (int t = nk * 4 + l; t < POST_NMS * 4; t += 64) out[t] = 0.f;
}

extern "C" void kernel_launch(void* const* d_in, const int* in_sizes, int n_in,
                              void* d_out, int out_size, void* d_ws, size_t ws_size,
                              hipStream_t stream) {
    const int N = in_sizes[0] / 2;             // 202500
    const float* cls = (const float*)d_in[0];
    const float* loc = (const float*)d_in[1];
    const float* anc = (const float*)d_in[2];
    float* out = (float*)d_out;

    char* ws = (char*)d_ws;
    size_t off = 0;
    auto take = [&](size_t bytes) {
        size_t o = off;
        off += (bytes + 255) & ~(size_t)255;
        return o;
    };
    // zero-init region: hist + meta/vmask (+ rank only on legacy path)
    unsigned* hist = (unsigned*)(ws + take((size_t)NBUCK * 4));      // 64 KB
    char*     mblk = ws + take(1024);
    unsigned* meta  = (unsigned*)mblk;                               // [0]=B [1]=count
    ull*      vmask = (ull*)(mblk + 256);                            // 94 words
    size_t zlen_fast = off;
    unsigned* rank = (unsigned*)(ws + take((size_t)CAP * 4));        // 32 KB (legacy only)
    size_t zlen_legacy = off;
    // rest
    ull*    cand   = (ull*)(ws + take((size_t)CAP * 8));             // 64 KB
    float4* topbox = (float4*)(ws + take((size_t)TB_PAD * 16));      // 94 KB
    // fast-path extras
    unsigned* keyc = (unsigned*)(ws + take((size_t)N * 4));          // 810 KB
    ull*      suppT = (ull*)(ws + take((size_t)KW * TB_PAD * 8));    // 4.52 MB
    ull*      sdg  = (ull*)(ws + take((size_t)TB_PAD * 8));          // 48 KB
    size_t full_need = off;
    const bool fast = (ws_size >= full_need);   // constant across calls -> graph-safe

    hipMemsetAsync(ws, 0, fast ? zlen_fast : zlen_legacy, stream);

    if (fast) {
        // 6-node graph: memset, score, compactB(findb inline), ranksc, supp, scan
        k_score<<<SBLK, 256, 0, stream>>>(cls, loc, anc, hist, keyc, N);
        k_compactB<<<CBLK, 256, 0, stream>>>(keyc, hist, meta, cand, N);
        k_ranksc<<<CAP / 32, 256, 0, stream>>>(cand, meta, loc, anc, topbox, vmask);
        k_supp<<<dim3(KW, KW), 64, 0, stream>>>(topbox, suppT, sdg);
        k_scan<<<1, 64, 0, stream>>>(suppT, sdg, vmask, topbox, out);
    } else {
        dim3 rgrid(CAP / (256 * RITEMS), CAP / RTILE);
        k_score<<<SBLK, 256, 0, stream>>>(cls, loc, anc, hist, (unsigned*)nullptr, N);
        k_findb<<<1, 1024, 0, stream>>>(hist, meta);
        k_compactR<<<(N + 255) / 256, 256, 0, stream>>>(cls, loc, anc, meta, cand, N);
        k_rank<<<rgrid, 256, 0, stream>>>(cand, meta, rank, topbox);
        k_scatter<<<CAP / 256, 256, 0, stream>>>(cand, meta, rank, loc, anc, topbox, vmask);
        k_nms<<<1, 64, 0, stream>>>(topbox, out);
    }
}